// Round 3
// baseline (641.225 us; speedup 1.0000x reference)
//
#include <hip/hip_runtime.h>
#include <math.h>

// Problem constants
#define BN 4
#define NNODE 100
#define TT 20
#define HH 64
#define OO 128
#define M (BN*NNODE*NNODE)   // 40000 edges
#define EPB 4                // edges per block (1 wave each, private LDS, no barriers)

// Workspace layout (float offsets)
#define WS_A1   0                       // A1[k][co], 3*64
#define WS_C3   192                     // c_t0[64], c_full[64], c_tL[64]
#define WS_W2F  384                     // w2 A-frags (f16): 24*512 halfs = 6144 floats
#define WS_WT1F (WS_W2F + 6144)         // Wt1 B-frags (f16): 8*512 halfs = 2048 floats
#define WS_DEN  (WS_WT1F + 2048)        // denom[4]
#define WS_EFA  (WS_DEN + 4)            // efa[M*64]
#define WS_ESC  (WS_EFA + M*64)         // exp(scores) [M]

typedef _Float16 half8 __attribute__((ext_vector_type(8)));
typedef float float4v __attribute__((ext_vector_type(4)));

// Pade(3,2): tanh(x) ~ x(15+x^2)/(15+6x^2), |err|<3e-4 for |x|<=1 (|x|~0.2 here)
__device__ __forceinline__ float pade_tanh(float x) {
    float x2 = x * x;
    return (x * (15.f + x2)) * __fdividef(1.f, fmaf(6.f, x2, 15.f));
}

// ---------------------------------------------------------------------------
// Kernel A: fold edge-embedding + conv1 into rank-1 constants; pack MFMA frags;
// zero the softmax denominators.
// ---------------------------------------------------------------------------
__global__ void prep_kernel(const float* __restrict__ W_edge,
                            const float* __restrict__ b_edge,
                            const float* __restrict__ w1,
                            const float* __restrict__ b1,
                            const float* __restrict__ w2,
                            const float* __restrict__ Wt1,
                            float* __restrict__ ws)
{
    const int tid  = blockIdx.x * blockDim.x + threadIdx.x;
    const int nthr = gridDim.x * blockDim.x;
    if (tid < 64) {
        int co = tid;
        float a[3] = {0.f, 0.f, 0.f};
        float bk[3] = {0.f, 0.f, 0.f};
        for (int ci = 0; ci < HH; ++ci) {
            float we = W_edge[ci], be = b_edge[ci];
#pragma unroll
            for (int k = 0; k < 3; ++k) {
                float w = w1[(co*HH + ci)*3 + k];
                a[k]  = fmaf(we, w, a[k]);
                bk[k] = fmaf(be, w, bk[k]);
            }
        }
        float bb = b1[co];
        ws[WS_A1 + 0*64 + co] = a[0];
        ws[WS_A1 + 1*64 + co] = a[1];
        ws[WS_A1 + 2*64 + co] = a[2];
        ws[WS_C3 +        co] = bb + bk[1] + bk[2];          // t == 0
        ws[WS_C3 +  64 +  co] = bb + bk[0] + bk[1] + bk[2];  // interior
        ws[WS_C3 + 128 +  co] = bb + bk[0] + bk[1];          // t == T-1
    } else if (tid < 68) {
        ws[WS_DEN + tid - 64] = 0.f;                          // zero denominators
    }
    _Float16* w2f  = (_Float16*)(ws + WS_W2F);
    _Float16* wt1f = (_Float16*)(ws + WS_WT1F);
    // w2 A-frags: co = mt*16+(lane&15), q = kt*32+(lane>>4)*8+j, q = k*64+ci
    for (int s = tid; s < 24*64*8; s += nthr) {
        int j    = s & 7;
        int lane = (s >> 3) & 63;
        int f    = s >> 9;           // 0..23
        int mt = f / 6, kt = f % 6;
        int co = mt*16 + (lane & 15);
        int q  = kt*32 + ((lane >> 4) << 3) + j;
        int k  = q >> 6, ci = q & 63;
        w2f[f*512 + lane*8 + j] = (_Float16)w2[(co*HH + ci)*3 + k];
    }
    // Wt1 B-frags: ci = kt*32+(lane>>4)*8+j, co = nt*16+(lane&15)
    for (int s = tid; s < 8*64*8; s += nthr) {
        int j    = s & 7;
        int lane = (s >> 3) & 63;
        int f    = s >> 9;           // 0..7
        int kt = f / 4, nt = f % 4;
        int ci = kt*32 + ((lane >> 4) << 3) + j;
        int co = nt*16 + (lane & 15);
        wt1f[f*512 + lane*8 + j] = (_Float16)Wt1[ci*HH + co];
    }
}

// ---------------------------------------------------------------------------
// Kernel B: 4 edges per block, one wave per edge, private LDS slices,
// NO barriers. conv1 (rank-1) -> conv2 (MFMA) -> temporal attn (MFMA +
// distributed softmax) -> efa + spatial exp-score (+atomic denom).
// ---------------------------------------------------------------------------
__launch_bounds__(EPB*64)
__global__ void edge_kernel(const float* __restrict__ ew_g,
                            const float* __restrict__ ws_c,
                            const float* __restrict__ b2,
                            const float* __restrict__ bt1,
                            const float* __restrict__ Wt2,
                            const float* __restrict__ bt2,
                            const float* __restrict__ Ws1,
                            const float* __restrict__ bs1,
                            const float* __restrict__ Ws2,
                            const float* __restrict__ bs2,
                            float* __restrict__ efa_g,
                            float* __restrict__ score_g,
                            float* __restrict__ den_g)
{
    // per-wave slices; row strides 72 halfs = 144 B (16B-aligned, 4 banks mod 32)
    __shared__ _Float16 y1p[EPB][22*72];  // padded y1: rows 0 and 21 are zero
    __shared__ _Float16 y2L[EPB][20*72];  // y2 [t][ci]
    __shared__ float    sbuf[EPB][20];
    __shared__ float    ewp[EPB][22];

    const int w    = threadIdx.x >> 6;
    const int lane = threadIdx.x & 63;
    const int m    = blockIdx.x * EPB + w;
    const int l15  = lane & 15;
    const int quad = lane >> 4;

    if (lane < TT)      ewp[w][lane + 1] = ew_g[m*TT + lane];
    else if (lane < 22) ewp[w][(lane - TT) * 21] = 0.f;   // lane20->[0], lane21->[21]

    const float a0 = ws_c[WS_A1 +       lane];
    const float a1 = ws_c[WS_A1 +  64 + lane];
    const float a2 = ws_c[WS_A1 + 128 + lane];
    const float c0 = ws_c[WS_C3 +       lane];
    const float cf = ws_c[WS_C3 +  64 + lane];
    const float cL = ws_c[WS_C3 + 128 + lane];

    // ---- conv1 (3 FMA per t) + relu -> padded LDS; lane = channel ci
    y1p[w][lane] = (_Float16)0.f;
    y1p[w][21*72 + lane] = (_Float16)0.f;
#pragma unroll
    for (int t = 0; t < TT; ++t) {
        float c = (t == 0) ? c0 : (t == TT-1) ? cL : cf;
        float v = fmaf(a0, ewp[w][t], fmaf(a1, ewp[w][t+1], fmaf(a2, ewp[w][t+2], c)));
        y1p[w][(t+1)*72 + lane] = (_Float16)fmaxf(v, 0.f);
    }

    // ---- conv2 GEMM: D[co=64, t=20pad32] = A[64,192] * B[192,t], 48 MFMAs
    // B-frag element q=kt*32+quad*8+j -> y1p[t + (kt>>1)][(kt&1)*32 + quad*8 + j]
    const _Float16* w2f = (const _Float16*)(ws_c + WS_W2F);
    float4v acc[4][2];
#pragma unroll
    for (int mt = 0; mt < 4; ++mt)
#pragma unroll
        for (int nt = 0; nt < 2; ++nt)
            acc[mt][nt] = float4v{0.f, 0.f, 0.f, 0.f};

    const int tB1 = (16 + l15 < TT) ? (16 + l15) : TT-1;  // clamped; garbage ignored
#pragma unroll
    for (int kt = 0; kt < 6; ++kt) {
        const int cofs = (kt & 1)*32 + quad*8;
        const int rofs = (kt >> 1);
        half8 b0 = *(const half8*)&y1p[w][(l15 + rofs)*72 + cofs];
        half8 b1 = *(const half8*)&y1p[w][(tB1 + rofs)*72 + cofs];
#pragma unroll
        for (int mt = 0; mt < 4; ++mt) {
            half8 a = *(const half8*)(w2f + ((mt*6 + kt)*64 + lane)*8);
            acc[mt][0] = __builtin_amdgcn_mfma_f32_16x16x32_f16(a, b0, acc[mt][0], 0, 0, 0);
            acc[mt][1] = __builtin_amdgcn_mfma_f32_16x16x32_f16(a, b1, acc[mt][1], 0, 0, 0);
        }
    }
    // bias + relu -> y2 (f16) in LDS [t][ci];  C layout: col t=l15, row co=mt*16+quad*4+reg
#pragma unroll
    for (int mt = 0; mt < 4; ++mt) {
#pragma unroll
        for (int reg = 0; reg < 4; ++reg) {
            int co = mt*16 + quad*4 + reg;
            float bb = b2[co];
            y2L[w][l15*72 + co] = (_Float16)fmaxf(acc[mt][0][reg] + bb, 0.f);
            if (l15 < TT - 16)
                y2L[w][(16 + l15)*72 + co] = (_Float16)fmaxf(acc[mt][1][reg] + bb, 0.f);
        }
    }

    // ---- Wt1 GEMM: U[t=20pad32, co=64] = y2[20,64] * Wt1[64,64], 16 MFMAs
    const _Float16* wt1f = (const _Float16*)(ws_c + WS_WT1F);
    float4v u[2][4];
#pragma unroll
    for (int mt = 0; mt < 2; ++mt)
#pragma unroll
        for (int nt = 0; nt < 4; ++nt)
            u[mt][nt] = float4v{0.f, 0.f, 0.f, 0.f};
#pragma unroll
    for (int kt = 0; kt < 2; ++kt) {
        half8 af0 = *(const half8*)&y2L[w][l15*72 + kt*32 + quad*8];
        half8 af1 = *(const half8*)&y2L[w][tB1*72 + kt*32 + quad*8];
#pragma unroll
        for (int nt = 0; nt < 4; ++nt) {
            half8 bf = *(const half8*)(wt1f + ((kt*4 + nt)*64 + lane)*8);
            u[0][nt] = __builtin_amdgcn_mfma_f32_16x16x32_f16(af0, bf, u[0][nt], 0, 0, 0);
            u[1][nt] = __builtin_amdgcn_mfma_f32_16x16x32_f16(af1, bf, u[1][nt], 0, 0, 0);
        }
    }

    // ---- s[t] = sum_co tanh(U[t,co]+bt1[co]) * Wt2[co]  (Pade tanh, quad-reduce)
    float bt1v[4], wt2v[4];
#pragma unroll
    for (int nt = 0; nt < 4; ++nt) {
        bt1v[nt] = bt1[nt*16 + l15];
        wt2v[nt] = Wt2[nt*16 + l15];
    }
#pragma unroll
    for (int mt = 0; mt < 2; ++mt) {
#pragma unroll
        for (int reg = 0; reg < 4; ++reg) {
            int t = mt*16 + quad*4 + reg;
            float p = 0.f;
#pragma unroll
            for (int nt = 0; nt < 4; ++nt) {
                float x = u[mt][nt][reg] + bt1v[nt];
                float x2 = x * x;
                p = fmaf(x * (15.f + x2),
                         __fdividef(wt2v[nt], fmaf(6.f, x2, 15.f)), p);
            }
            p += __shfl_xor(p, 1, 64);
            p += __shfl_xor(p, 2, 64);
            p += __shfl_xor(p, 4, 64);
            p += __shfl_xor(p, 8, 64);
            if (l15 == 0 && t < TT) sbuf[w][t] = p;
        }
    }

    // ---- distributed softmax over T: lane t holds exp; broadcast via shfl
    float sv = (lane < TT) ? (sbuf[w][lane] + bt2[0]) : -1e30f;
    float mx = sv;
#pragma unroll
    for (int off = 32; off >= 1; off >>= 1)
        mx = fmaxf(mx, __shfl_xor(mx, off, 64));
    float ev = (lane < TT) ? __expf(sv - mx) : 0.f;
    float sum = ev;
#pragma unroll
    for (int off = 32; off >= 1; off >>= 1)
        sum += __shfl_xor(sum, off, 64);
    float inv = __fdividef(1.f, sum);

    float efa = 0.f;
#pragma unroll
    for (int t = 0; t < TT; ++t)
        efa = fmaf((float)y2L[w][t*72 + lane], __shfl(ev, t, 64), efa);
    efa *= inv;
    efa_g[m*64 + lane] = efa;

    // ---- spatial score: us = efa . Ws1[:,lane] + bs1 (4-way split chains)
    float p0 = bs1[lane], p1 = 0.f, p2 = 0.f, p3 = 0.f;
#pragma unroll
    for (int ci = 0; ci < HH; ci += 4) {
        p0 = fmaf(__shfl(efa, ci + 0, 64), Ws1[(ci + 0)*HH + lane], p0);
        p1 = fmaf(__shfl(efa, ci + 1, 64), Ws1[(ci + 1)*HH + lane], p1);
        p2 = fmaf(__shfl(efa, ci + 2, 64), Ws1[(ci + 2)*HH + lane], p2);
        p3 = fmaf(__shfl(efa, ci + 3, 64), Ws1[(ci + 3)*HH + lane], p3);
    }
    float us = (p0 + p1) + (p2 + p3);
    float v = pade_tanh(us) * Ws2[lane];
#pragma unroll
    for (int off = 32; off >= 1; off >>= 1)
        v += __shfl_xor(v, off, 64);
    if (lane == 0) {
        float es = __expf(v + bs2[0]);   // |v| ~ 0.5 -> safe without max-sub
        score_g[m] = es;
        atomicAdd(&den_g[m / (NNODE*NNODE)], es);
    }
}

// ---------------------------------------------------------------------------
// Kernel C: node aggregation (4 waves split j) + 3-layer MLP (wave 0).
// ---------------------------------------------------------------------------
__launch_bounds__(256)
__global__ void node_kernel(const float* __restrict__ efa_g,
                            const float* __restrict__ e_g,
                            const float* __restrict__ den_g,
                            const float* __restrict__ Wg1,
                            const float* __restrict__ bg1,
                            const float* __restrict__ Wg2,
                            const float* __restrict__ bg2,
                            const float* __restrict__ Wout,
                            const float* __restrict__ bout,
                            float* __restrict__ out)
{
    __shared__ float part[4][64];
    const int bi   = blockIdx.x;        // b*100 + i
    const int b    = bi / NNODE;
    const int lane = threadIdx.x & 63;
    const int w    = threadIdx.x >> 6;
    const int base = bi * NNODE;

    float acc0 = 0.f, acc1 = 0.f;
    for (int j = w; j < NNODE; j += 8) {
        acc0 = fmaf(e_g[base + j], efa_g[(base + j)*64 + lane], acc0);
        int j2 = j + 4;
        if (j2 < NNODE)
            acc1 = fmaf(e_g[base + j2], efa_g[(base + j2)*64 + lane], acc1);
    }
    part[w][lane] = acc0 + acc1;
    __syncthreads();
    if (w != 0) return;

    const float invden = __fdividef(1.f, den_g[b]);
    float node = (part[0][lane] + part[1][lane] + part[2][lane] + part[3][lane]) * invden;

    float a0 = bg1[lane], a1 = 0.f, a2 = 0.f, a3 = 0.f;
#pragma unroll
    for (int ci = 0; ci < HH; ci += 4) {
        a0 = fmaf(__shfl(node, ci + 0, 64), Wg1[(ci + 0)*HH + lane], a0);
        a1 = fmaf(__shfl(node, ci + 1, 64), Wg1[(ci + 1)*HH + lane], a1);
        a2 = fmaf(__shfl(node, ci + 2, 64), Wg1[(ci + 2)*HH + lane], a2);
        a3 = fmaf(__shfl(node, ci + 3, 64), Wg1[(ci + 3)*HH + lane], a3);
    }
    float g1 = fmaxf((a0 + a1) + (a2 + a3), 0.f);

    a0 = bg2[lane]; a1 = 0.f; a2 = 0.f; a3 = 0.f;
#pragma unroll
    for (int ci = 0; ci < HH; ci += 4) {
        a0 = fmaf(__shfl(g1, ci + 0, 64), Wg2[(ci + 0)*HH + lane], a0);
        a1 = fmaf(__shfl(g1, ci + 1, 64), Wg2[(ci + 1)*HH + lane], a1);
        a2 = fmaf(__shfl(g1, ci + 2, 64), Wg2[(ci + 2)*HH + lane], a2);
        a3 = fmaf(__shfl(g1, ci + 3, 64), Wg2[(ci + 3)*HH + lane], a3);
    }
    float g2 = fmaxf((a0 + a1) + (a2 + a3), 0.f);

    float o0 = bout[lane], o1 = bout[lane + 64];
    float q0 = 0.f, q1 = 0.f;
#pragma unroll
    for (int ci = 0; ci < HH; ci += 2) {
        float ga = __shfl(g2, ci, 64), gb = __shfl(g2, ci + 1, 64);
        o0 = fmaf(ga, Wout[ci*OO + lane],            o0);
        o1 = fmaf(ga, Wout[ci*OO + lane + 64],       o1);
        q0 = fmaf(gb, Wout[(ci + 1)*OO + lane],      q0);
        q1 = fmaf(gb, Wout[(ci + 1)*OO + lane + 64], q1);
    }
    out[bi*OO + lane]      = fmaxf(o0 + q0, 0.f);
    out[bi*OO + lane + 64] = fmaxf(o1 + q1, 0.f);
}

// ---------------------------------------------------------------------------
extern "C" void kernel_launch(void* const* d_in, const int* in_sizes, int n_in,
                              void* d_out, int out_size, void* d_ws, size_t ws_size,
                              hipStream_t stream)
{
    const float* ew      = (const float*)d_in[0];
    const float* W_edge  = (const float*)d_in[1];
    const float* b_edge  = (const float*)d_in[2];
    const float* conv1_w = (const float*)d_in[3];
    const float* conv1_b = (const float*)d_in[4];
    const float* conv2_w = (const float*)d_in[5];
    const float* conv2_b = (const float*)d_in[6];
    const float* Wt1     = (const float*)d_in[7];
    const float* bt1     = (const float*)d_in[8];
    const float* Wt2     = (const float*)d_in[9];
    const float* bt2     = (const float*)d_in[10];
    const float* Ws1     = (const float*)d_in[11];
    const float* bs1     = (const float*)d_in[12];
    const float* Ws2     = (const float*)d_in[13];
    const float* bs2     = (const float*)d_in[14];
    const float* Wg1     = (const float*)d_in[15];
    const float* bg1     = (const float*)d_in[16];
    const float* Wg2     = (const float*)d_in[17];
    const float* bg2     = (const float*)d_in[18];
    const float* Wout    = (const float*)d_in[19];
    const float* bout    = (const float*)d_in[20];

    float* ws  = (float*)d_ws;
    float* out = (float*)d_out;

    prep_kernel<<<16, 256, 0, stream>>>(W_edge, b_edge, conv1_w, conv1_b, conv2_w, Wt1, ws);

    edge_kernel<<<M/EPB, EPB*64, 0, stream>>>(ew, ws, conv2_b,
                                              bt1, Wt2, bt2,
                                              Ws1, bs1, Ws2, bs2,
                                              ws + WS_EFA, ws + WS_ESC, ws + WS_DEN);

    node_kernel<<<BN*NNODE, 256, 0, stream>>>(ws + WS_EFA, ws + WS_ESC, ws + WS_DEN,
                                              Wg1, bg1, Wg2, bg2, Wout, bout, out);
}

// Round 4
// 268.874 us; speedup vs baseline: 2.3849x; 2.3849x over previous
//
#include <hip/hip_runtime.h>
#include <math.h>

// Problem constants
#define BN 4
#define NNODE 100
#define TT 20
#define HH 64
#define OO 128
#define M (BN*NNODE*NNODE)   // 40000 edges

// Workspace layout (float offsets)
#define WS_A1   0                       // A1[k][co], 3*64
#define WS_C3   192                     // c_t0[64], c_full[64], c_tL[64]
#define WS_W2F  384                     // w2 A-frags (f16): 24*512 halfs = 6144 floats
#define WS_WT1F (WS_W2F + 6144)         // Wt1 B-frags (f16): 8*512 halfs = 2048 floats
#define WS_DEN  (WS_WT1F + 2048)        // denom[4]
#define WS_EFA  (WS_DEN + 4)            // efa[M*64]
#define WS_ESC  (WS_EFA + M*64)         // exp(scores) [M]

typedef _Float16 half8 __attribute__((ext_vector_type(8)));
typedef float float4v __attribute__((ext_vector_type(4)));

// Pade(3,2): tanh(x) ~ x(15+x^2)/(15+6x^2), |err|<3e-4 for |x|<=1 (|x|~0.2 here)
__device__ __forceinline__ float pade_tanh(float x) {
    float x2 = x * x;
    return (x * (15.f + x2)) * __fdividef(1.f, fmaf(6.f, x2, 15.f));
}

// ---------------------------------------------------------------------------
// Kernel A: fold edge-embedding + conv1 into rank-1 constants; pack MFMA frags.
// ---------------------------------------------------------------------------
__global__ void prep_kernel(const float* __restrict__ W_edge,
                            const float* __restrict__ b_edge,
                            const float* __restrict__ w1,
                            const float* __restrict__ b1,
                            const float* __restrict__ w2,
                            const float* __restrict__ Wt1,
                            float* __restrict__ ws)
{
    const int tid  = blockIdx.x * blockDim.x + threadIdx.x;
    const int nthr = gridDim.x * blockDim.x;
    if (tid < 64) {
        int co = tid;
        float a[3] = {0.f, 0.f, 0.f};
        float bk[3] = {0.f, 0.f, 0.f};
        for (int ci = 0; ci < HH; ++ci) {
            float we = W_edge[ci], be = b_edge[ci];
#pragma unroll
            for (int k = 0; k < 3; ++k) {
                float w = w1[(co*HH + ci)*3 + k];
                a[k]  = fmaf(we, w, a[k]);
                bk[k] = fmaf(be, w, bk[k]);
            }
        }
        float bb = b1[co];
        ws[WS_A1 + 0*64 + co] = a[0];
        ws[WS_A1 + 1*64 + co] = a[1];
        ws[WS_A1 + 2*64 + co] = a[2];
        ws[WS_C3 +        co] = bb + bk[1] + bk[2];          // t == 0
        ws[WS_C3 +  64 +  co] = bb + bk[0] + bk[1] + bk[2];  // interior
        ws[WS_C3 + 128 +  co] = bb + bk[0] + bk[1];          // t == T-1
    }
    _Float16* w2f  = (_Float16*)(ws + WS_W2F);
    _Float16* wt1f = (_Float16*)(ws + WS_WT1F);
    // w2 A-frags: co = mt*16+(lane&15), q = kt*32+(lane>>4)*8+j, q = k*64+ci
    for (int s = tid; s < 24*64*8; s += nthr) {
        int j    = s & 7;
        int lane = (s >> 3) & 63;
        int f    = s >> 9;           // 0..23
        int mt = f / 6, kt = f % 6;
        int co = mt*16 + (lane & 15);
        int q  = kt*32 + ((lane >> 4) << 3) + j;
        int k  = q >> 6, ci = q & 63;
        w2f[f*512 + lane*8 + j] = (_Float16)w2[(co*HH + ci)*3 + k];
    }
    // Wt1 B-frags: ci = kt*32+(lane>>4)*8+j, co = nt*16+(lane&15)
    for (int s = tid; s < 8*64*8; s += nthr) {
        int j    = s & 7;
        int lane = (s >> 3) & 63;
        int f    = s >> 9;           // 0..7
        int kt = f / 4, nt = f % 4;
        int ci = kt*32 + ((lane >> 4) << 3) + j;
        int co = nt*16 + (lane & 15);
        wt1f[f*512 + lane*8 + j] = (_Float16)Wt1[ci*HH + co];
    }
}

// ---------------------------------------------------------------------------
// Kernel B: one wave per edge (R2-proven structure). conv1 (rank-1, fp32) ->
// conv2 (MFMA f16) -> temporal attention (MFMA + distributed softmax) ->
// efa + spatial exp-score. NO atomics.
// ---------------------------------------------------------------------------
__launch_bounds__(64)
__global__ void edge_kernel(const float* __restrict__ ew_g,
                            const float* __restrict__ ws_c,
                            const float* __restrict__ b2,
                            const float* __restrict__ bt1,
                            const float* __restrict__ Wt2,
                            const float* __restrict__ bt2,
                            const float* __restrict__ Ws1,
                            const float* __restrict__ bs1,
                            const float* __restrict__ Ws2,
                            const float* __restrict__ bs2,
                            float* __restrict__ efa_g,
                            float* __restrict__ score_g)
{
    __shared__ _Float16 y1B[TT*192];   // [t][q], q = k*64+ci  (7680 B)
    __shared__ _Float16 y2L[TT*72];    // [t][ci], stride 72 halfs (2880 B)
    __shared__ float    sbuf[TT];
    __shared__ float    ewp[22];

    const int m    = blockIdx.x;
    const int lane = threadIdx.x;       // 0..63
    const int l15  = lane & 15;
    const int quad = lane >> 4;

    if (lane < TT) ewp[lane + 1] = ew_g[m*TT + lane];
    if (lane == 0) { ewp[0] = 0.f; ewp[21] = 0.f; }

    const float a0 = ws_c[WS_A1 +       lane];
    const float a1 = ws_c[WS_A1 +  64 + lane];
    const float a2 = ws_c[WS_A1 + 128 + lane];
    const float c0 = ws_c[WS_C3 +       lane];
    const float cf = ws_c[WS_C3 +  64 + lane];
    const float cL = ws_c[WS_C3 + 128 + lane];
    __syncthreads();

    // ---- conv1 (3 FMA per t) + relu; lane = channel ci here
    float y1v[TT];
#pragma unroll
    for (int t = 0; t < TT; ++t) {
        float c = (t == 0) ? c0 : (t == TT-1) ? cL : cf;
        y1v[t] = fmaxf(fmaf(a0, ewp[t], fmaf(a1, ewp[t+1], fmaf(a2, ewp[t+2], c))), 0.f);
    }
    // pack B for conv2: y1B[t][k*64+ci] = y1p[t+k-1][ci]
#pragma unroll
    for (int t = 0; t < TT; ++t) {
        y1B[t*192 +       lane] = (_Float16)((t >= 1)    ? y1v[t-1] : 0.f);
        y1B[t*192 +  64 + lane] = (_Float16)y1v[t];
        y1B[t*192 + 128 + lane] = (_Float16)((t < TT-1)  ? y1v[t+1] : 0.f);
    }
    __syncthreads();

    // ---- conv2 GEMM: D[co=64, t=20pad32] = A[64,192] * B[192,t], 48 MFMAs
    const _Float16* w2f = (const _Float16*)(ws_c + WS_W2F);
    float4v acc[4][2];
#pragma unroll
    for (int mt = 0; mt < 4; ++mt)
#pragma unroll
        for (int nt = 0; nt < 2; ++nt)
            acc[mt][nt] = float4v{0.f, 0.f, 0.f, 0.f};

    const int tB0 = l15;                                  // 0..15 (valid)
    const int tB1 = (16 + l15 < TT) ? (16 + l15) : TT-1;  // clamped; garbage ignored
#pragma unroll
    for (int kt = 0; kt < 6; ++kt) {
        half8 b0 = *(const half8*)&y1B[tB0*192 + kt*32 + quad*8];
        half8 b1 = *(const half8*)&y1B[tB1*192 + kt*32 + quad*8];
#pragma unroll
        for (int mt = 0; mt < 4; ++mt) {
            half8 a = *(const half8*)(w2f + ((mt*6 + kt)*64 + lane)*8);
            acc[mt][0] = __builtin_amdgcn_mfma_f32_16x16x32_f16(a, b0, acc[mt][0], 0, 0, 0);
            acc[mt][1] = __builtin_amdgcn_mfma_f32_16x16x32_f16(a, b1, acc[mt][1], 0, 0, 0);
        }
    }
    // bias + relu -> y2 (f16) in LDS [t][ci]; C layout: col t=l15, row co=mt*16+quad*4+reg
#pragma unroll
    for (int mt = 0; mt < 4; ++mt) {
#pragma unroll
        for (int reg = 0; reg < 4; ++reg) {
            int co = mt*16 + quad*4 + reg;
            float bb = b2[co];
            y2L[l15*72 + co] = (_Float16)fmaxf(acc[mt][0][reg] + bb, 0.f);
            if (l15 < TT - 16)
                y2L[(16 + l15)*72 + co] = (_Float16)fmaxf(acc[mt][1][reg] + bb, 0.f);
        }
    }
    __syncthreads();

    // ---- Wt1 GEMM: U[t=20pad32, co=64] = y2[20,64] * Wt1[64,64], 16 MFMAs
    const _Float16* wt1f = (const _Float16*)(ws_c + WS_WT1F);
    float4v u[2][4];
#pragma unroll
    for (int mt = 0; mt < 2; ++mt)
#pragma unroll
        for (int nt = 0; nt < 4; ++nt)
            u[mt][nt] = float4v{0.f, 0.f, 0.f, 0.f};
#pragma unroll
    for (int kt = 0; kt < 2; ++kt) {
        half8 af0 = *(const half8*)&y2L[tB0*72 + kt*32 + quad*8];
        half8 af1 = *(const half8*)&y2L[tB1*72 + kt*32 + quad*8];
#pragma unroll
        for (int nt = 0; nt < 4; ++nt) {
            half8 bf = *(const half8*)(wt1f + ((kt*4 + nt)*64 + lane)*8);
            u[0][nt] = __builtin_amdgcn_mfma_f32_16x16x32_f16(af0, bf, u[0][nt], 0, 0, 0);
            u[1][nt] = __builtin_amdgcn_mfma_f32_16x16x32_f16(af1, bf, u[1][nt], 0, 0, 0);
        }
    }

    // ---- s[t] = sum_co tanh(U[t,co]+bt1[co]) * Wt2[co]  (Pade tanh, quad-reduce)
    float bt1v[4], wt2v[4];
#pragma unroll
    for (int nt = 0; nt < 4; ++nt) {
        bt1v[nt] = bt1[nt*16 + l15];
        wt2v[nt] = Wt2[nt*16 + l15];
    }
#pragma unroll
    for (int mt = 0; mt < 2; ++mt) {
#pragma unroll
        for (int reg = 0; reg < 4; ++reg) {
            int t = mt*16 + quad*4 + reg;
            float p = 0.f;
#pragma unroll
            for (int nt = 0; nt < 4; ++nt) {
                float x = u[mt][nt][reg] + bt1v[nt];
                float x2 = x * x;
                p = fmaf(x * (15.f + x2),
                         __fdividef(wt2v[nt], fmaf(6.f, x2, 15.f)), p);
            }
            p += __shfl_xor(p, 1, 64);
            p += __shfl_xor(p, 2, 64);
            p += __shfl_xor(p, 4, 64);
            p += __shfl_xor(p, 8, 64);
            if (l15 == 0 && t < TT) sbuf[t] = p;
        }
    }
    __syncthreads();

    // ---- distributed softmax over T: lane t holds exp; broadcast via shfl
    float sv = (lane < TT) ? (sbuf[lane] + bt2[0]) : -1e30f;
    float mx = sv;
#pragma unroll
    for (int off = 32; off >= 1; off >>= 1)
        mx = fmaxf(mx, __shfl_xor(mx, off, 64));
    float ev = (lane < TT) ? __expf(sv - mx) : 0.f;
    float sum = ev;
#pragma unroll
    for (int off = 32; off >= 1; off >>= 1)
        sum += __shfl_xor(sum, off, 64);
    float inv = __fdividef(1.f, sum);

    float efa = 0.f;
#pragma unroll
    for (int t = 0; t < TT; ++t)
        efa = fmaf((float)y2L[t*72 + lane], __shfl(ev, t, 64), efa);
    efa *= inv;
    efa_g[m*64 + lane] = efa;

    // ---- spatial score: us = efa . Ws1[:,lane] + bs1 (4-way split chains)
    float p0 = bs1[lane], p1 = 0.f, p2 = 0.f, p3 = 0.f;
#pragma unroll
    for (int ci = 0; ci < HH; ci += 4) {
        p0 = fmaf(__shfl(efa, ci + 0, 64), Ws1[(ci + 0)*HH + lane], p0);
        p1 = fmaf(__shfl(efa, ci + 1, 64), Ws1[(ci + 1)*HH + lane], p1);
        p2 = fmaf(__shfl(efa, ci + 2, 64), Ws1[(ci + 2)*HH + lane], p2);
        p3 = fmaf(__shfl(efa, ci + 3, 64), Ws1[(ci + 3)*HH + lane], p3);
    }
    float us = (p0 + p1) + (p2 + p3);
    float v = pade_tanh(us) * Ws2[lane];
#pragma unroll
    for (int off = 32; off >= 1; off >>= 1)
        v += __shfl_xor(v, off, 64);
    if (lane == 0)
        score_g[m] = __expf(v + bs2[0]);   // |v| small -> safe without max-sub
}

// ---------------------------------------------------------------------------
// Kernel C: per-batch sum of exp-scores -> denom[4]. 4 blocks.
// ---------------------------------------------------------------------------
__global__ void denom_kernel(const float* __restrict__ score_g,
                             float* __restrict__ den_g)
{
    const int b = blockIdx.x;
    const int tid = threadIdx.x;     // 256
    __shared__ float red[256];
    float sum = 0.f;
    for (int i = tid; i < NNODE*NNODE; i += 256)
        sum += score_g[b*NNODE*NNODE + i];
    red[tid] = sum; __syncthreads();
    for (int w = 128; w >= 1; w >>= 1) {
        if (tid < w) red[tid] += red[tid + w];
        __syncthreads();
    }
    if (tid == 0) den_g[b] = red[0];
}

// ---------------------------------------------------------------------------
// Kernel D: node aggregation (waves split j) + 3-layer MLP (wave 0).
// ---------------------------------------------------------------------------
__launch_bounds__(256)
__global__ void node_kernel(const float* __restrict__ efa_g,
                            const float* __restrict__ e_g,
                            const float* __restrict__ den_g,
                            const float* __restrict__ Wg1,
                            const float* __restrict__ bg1,
                            const float* __restrict__ Wg2,
                            const float* __restrict__ bg2,
                            const float* __restrict__ Wout,
                            const float* __restrict__ bout,
                            float* __restrict__ out)
{
    __shared__ float part[4][64];
    const int bi   = blockIdx.x;        // b*100 + i
    const int b    = bi / NNODE;
    const int lane = threadIdx.x & 63;
    const int w    = threadIdx.x >> 6;
    const int base = bi * NNODE;

    float acc0 = 0.f, acc1 = 0.f;
    for (int j = w; j < NNODE; j += 8) {
        acc0 = fmaf(e_g[base + j], efa_g[(base + j)*64 + lane], acc0);
        int j2 = j + 4;
        if (j2 < NNODE)
            acc1 = fmaf(e_g[base + j2], efa_g[(base + j2)*64 + lane], acc1);
    }
    part[w][lane] = acc0 + acc1;
    __syncthreads();
    if (w != 0) return;

    const float invden = __fdividef(1.f, den_g[b]);
    float node = (part[0][lane] + part[1][lane] + part[2][lane] + part[3][lane]) * invden;

    float a0 = bg1[lane], a1 = 0.f, a2 = 0.f, a3 = 0.f;
#pragma unroll
    for (int ci = 0; ci < HH; ci += 4) {
        a0 = fmaf(__shfl(node, ci + 0, 64), Wg1[(ci + 0)*HH + lane], a0);
        a1 = fmaf(__shfl(node, ci + 1, 64), Wg1[(ci + 1)*HH + lane], a1);
        a2 = fmaf(__shfl(node, ci + 2, 64), Wg1[(ci + 2)*HH + lane], a2);
        a3 = fmaf(__shfl(node, ci + 3, 64), Wg1[(ci + 3)*HH + lane], a3);
    }
    float g1 = fmaxf((a0 + a1) + (a2 + a3), 0.f);

    a0 = bg2[lane]; a1 = 0.f; a2 = 0.f; a3 = 0.f;
#pragma unroll
    for (int ci = 0; ci < HH; ci += 4) {
        a0 = fmaf(__shfl(g1, ci + 0, 64), Wg2[(ci + 0)*HH + lane], a0);
        a1 = fmaf(__shfl(g1, ci + 1, 64), Wg2[(ci + 1)*HH + lane], a1);
        a2 = fmaf(__shfl(g1, ci + 2, 64), Wg2[(ci + 2)*HH + lane], a2);
        a3 = fmaf(__shfl(g1, ci + 3, 64), Wg2[(ci + 3)*HH + lane], a3);
    }
    float g2 = fmaxf((a0 + a1) + (a2 + a3), 0.f);

    float o0 = bout[lane], o1 = bout[lane + 64];
    float q0 = 0.f, q1 = 0.f;
#pragma unroll
    for (int ci = 0; ci < HH; ci += 2) {
        float ga = __shfl(g2, ci, 64), gb = __shfl(g2, ci + 1, 64);
        o0 = fmaf(ga, Wout[ci*OO + lane],            o0);
        o1 = fmaf(ga, Wout[ci*OO + lane + 64],       o1);
        q0 = fmaf(gb, Wout[(ci + 1)*OO + lane],      q0);
        q1 = fmaf(gb, Wout[(ci + 1)*OO + lane + 64], q1);
    }
    out[bi*OO + lane]      = fmaxf(o0 + q0, 0.f);
    out[bi*OO + lane + 64] = fmaxf(o1 + q1, 0.f);
}

// ---------------------------------------------------------------------------
extern "C" void kernel_launch(void* const* d_in, const int* in_sizes, int n_in,
                              void* d_out, int out_size, void* d_ws, size_t ws_size,
                              hipStream_t stream)
{
    const float* ew      = (const float*)d_in[0];
    const float* W_edge  = (const float*)d_in[1];
    const float* b_edge  = (const float*)d_in[2];
    const float* conv1_w = (const float*)d_in[3];
    const float* conv1_b = (const float*)d_in[4];
    const float* conv2_w = (const float*)d_in[5];
    const float* conv2_b = (const float*)d_in[6];
    const float* Wt1     = (const float*)d_in[7];
    const float* bt1     = (const float*)d_in[8];
    const float* Wt2     = (const float*)d_in[9];
    const float* bt2     = (const float*)d_in[10];
    const float* Ws1     = (const float*)d_in[11];
    const float* bs1     = (const float*)d_in[12];
    const float* Ws2     = (const float*)d_in[13];
    const float* bs2     = (const float*)d_in[14];
    const float* Wg1     = (const float*)d_in[15];
    const float* bg1     = (const float*)d_in[16];
    const float* Wg2     = (const float*)d_in[17];
    const float* bg2     = (const float*)d_in[18];
    const float* Wout    = (const float*)d_in[19];
    const float* bout    = (const float*)d_in[20];

    float* ws  = (float*)d_ws;
    float* out = (float*)d_out;

    prep_kernel<<<16, 256, 0, stream>>>(W_edge, b_edge, conv1_w, conv1_b, conv2_w, Wt1, ws);

    edge_kernel<<<M, 64, 0, stream>>>(ew, ws, conv2_b,
                                      bt1, Wt2, bt2,
                                      Ws1, bs1, Ws2, bs2,
                                      ws + WS_EFA, ws + WS_ESC);

    denom_kernel<<<BN, 256, 0, stream>>>(ws + WS_ESC, ws + WS_DEN);

    node_kernel<<<BN*NNODE, 256, 0, stream>>>(ws + WS_EFA, ws + WS_ESC, ws + WS_DEN,
                                              Wg1, bg1, Wg2, bg2, Wout, bout, out);
}

// Round 5
// 239.059 us; speedup vs baseline: 2.6823x; 1.1247x over previous
//
#include <hip/hip_runtime.h>
#include <math.h>

// Problem constants
#define BN 4
#define NNODE 100
#define TT 20
#define HH 64
#define OO 128
#define M (BN*NNODE*NNODE)   // 40000 edges

// Workspace layout (float offsets)
#define WS_A1   0                       // A1[k][co], 3*64
#define WS_C3   192                     // c_t0[64], c_full[64], c_tL[64]
#define WS_W2F  384                     // w2 A-frags (f16): 24*512 halfs = 6144 floats
#define WS_WT1F (WS_W2F + 6144)         // Wt1 B-frags (f16): 8*512 halfs = 2048 floats
#define WS_WS1F (WS_WT1F + 2048)        // Ws1 B-frags (f16): 8*512 halfs = 2048 floats
#define WS_DEN  (WS_WS1F + 2048)        // denom[4]
#define WS_EFA  (WS_DEN + 4)            // efa[M*64]
#define WS_ESC  (WS_EFA + M*64)         // exp(scores) [M]

typedef _Float16 half8 __attribute__((ext_vector_type(8)));
typedef float float4v __attribute__((ext_vector_type(4)));

// Pade(3,2): tanh(x) ~ x(15+x^2)/(15+6x^2), |err|<3e-4 for |x|<=1 (|x|~0.2 here)
__device__ __forceinline__ float pade_tanh(float x) {
    float x2 = x * x;
    return (x * (15.f + x2)) * __fdividef(1.f, fmaf(6.f, x2, 15.f));
}

// ---------------------------------------------------------------------------
// Kernel A: fold edge-embedding + conv1 into rank-1 constants; pack MFMA frags
// for w2 (A-operand), Wt1 (B-operand), Ws1 (B-operand).
// ---------------------------------------------------------------------------
__global__ void prep_kernel(const float* __restrict__ W_edge,
                            const float* __restrict__ b_edge,
                            const float* __restrict__ w1,
                            const float* __restrict__ b1,
                            const float* __restrict__ w2,
                            const float* __restrict__ Wt1,
                            const float* __restrict__ Ws1,
                            float* __restrict__ ws)
{
    const int tid  = blockIdx.x * blockDim.x + threadIdx.x;
    const int nthr = gridDim.x * blockDim.x;
    if (tid < 64) {
        int co = tid;
        float a[3] = {0.f, 0.f, 0.f};
        float bk[3] = {0.f, 0.f, 0.f};
        for (int ci = 0; ci < HH; ++ci) {
            float we = W_edge[ci], be = b_edge[ci];
#pragma unroll
            for (int k = 0; k < 3; ++k) {
                float w = w1[(co*HH + ci)*3 + k];
                a[k]  = fmaf(we, w, a[k]);
                bk[k] = fmaf(be, w, bk[k]);
            }
        }
        float bb = b1[co];
        ws[WS_A1 + 0*64 + co] = a[0];
        ws[WS_A1 + 1*64 + co] = a[1];
        ws[WS_A1 + 2*64 + co] = a[2];
        ws[WS_C3 +        co] = bb + bk[1] + bk[2];          // t == 0
        ws[WS_C3 +  64 +  co] = bb + bk[0] + bk[1] + bk[2];  // interior
        ws[WS_C3 + 128 +  co] = bb + bk[0] + bk[1];          // t == T-1
    }
    _Float16* w2f  = (_Float16*)(ws + WS_W2F);
    _Float16* wt1f = (_Float16*)(ws + WS_WT1F);
    _Float16* ws1f = (_Float16*)(ws + WS_WS1F);
    // w2 A-frags: co = mt*16+(lane&15), q = kt*32+(lane>>4)*8+j, q = k*64+ci
    for (int s = tid; s < 24*64*8; s += nthr) {
        int j    = s & 7;
        int lane = (s >> 3) & 63;
        int f    = s >> 9;           // 0..23
        int mt = f / 6, kt = f % 6;
        int co = mt*16 + (lane & 15);
        int q  = kt*32 + ((lane >> 4) << 3) + j;
        int k  = q >> 6, ci = q & 63;
        w2f[f*512 + lane*8 + j] = (_Float16)w2[(co*HH + ci)*3 + k];
    }
    // Wt1 / Ws1 B-frags: ci = kt*32+(lane>>4)*8+j, co = nt*16+(lane&15)
    for (int s = tid; s < 8*64*8; s += nthr) {
        int j    = s & 7;
        int lane = (s >> 3) & 63;
        int f    = s >> 9;           // 0..7
        int kt = f / 4, nt = f % 4;
        int ci = kt*32 + ((lane >> 4) << 3) + j;
        int co = nt*16 + (lane & 15);
        wt1f[f*512 + lane*8 + j] = (_Float16)Wt1[ci*HH + co];
        ws1f[f*512 + lane*8 + j] = (_Float16)Ws1[ci*HH + co];
    }
}

// ---------------------------------------------------------------------------
// Kernel B: one wave per edge. conv1 (rank-1, fp32) -> conv2 (MFMA f16,
// shifted-window B reads from padded y1p) -> temporal attention (MFMA +
// distributed softmax) -> efa + spatial score (8-MFMA matvec). NO atomics.
// LDS ~6.2 KB/block -> ~25 blocks/CU.
// ---------------------------------------------------------------------------
__launch_bounds__(64)
__global__ void edge_kernel(const float* __restrict__ ew_g,
                            const float* __restrict__ ws_c,
                            const float* __restrict__ b2,
                            const float* __restrict__ bt1,
                            const float* __restrict__ Wt2,
                            const float* __restrict__ bt2,
                            const float* __restrict__ bs1,
                            const float* __restrict__ Ws2,
                            const float* __restrict__ bs2,
                            float* __restrict__ efa_g,
                            float* __restrict__ score_g)
{
    __shared__ _Float16 y1p[22*72];    // padded y1 rows 0/21 zero, stride 72 (3168 B)
    __shared__ _Float16 y2L[TT*72];    // y2 [t][ci], stride 72 (2880 B)
    __shared__ float    sbuf[TT];
    __shared__ float    ewp[22];

    const int m    = blockIdx.x;
    const int lane = threadIdx.x;       // 0..63
    const int l15  = lane & 15;
    const int quad = lane >> 4;

    if (lane < TT) ewp[lane + 1] = ew_g[m*TT + lane];
    if (lane == 0) { ewp[0] = 0.f; ewp[21] = 0.f; }

    const float a0 = ws_c[WS_A1 +       lane];
    const float a1 = ws_c[WS_A1 +  64 + lane];
    const float a2 = ws_c[WS_A1 + 128 + lane];
    const float c0 = ws_c[WS_C3 +       lane];
    const float cf = ws_c[WS_C3 +  64 + lane];
    const float cL = ws_c[WS_C3 + 128 + lane];
    __syncthreads();

    // ---- conv1 (3 FMA per t) + relu -> padded LDS; lane = channel ci
    y1p[lane] = (_Float16)0.f;          // row 0
    y1p[21*72 + lane] = (_Float16)0.f;  // row 21
#pragma unroll
    for (int t = 0; t < TT; ++t) {
        float c = (t == 0) ? c0 : (t == TT-1) ? cL : cf;
        float v = fmaf(a0, ewp[t], fmaf(a1, ewp[t+1], fmaf(a2, ewp[t+2], c)));
        y1p[(t+1)*72 + lane] = (_Float16)fmaxf(v, 0.f);
    }
    __syncthreads();

    // ---- conv2 GEMM: D[co=64, t=20pad32] = A[64,192] * B[192,t], 48 MFMAs
    // B elem q=kt*32+quad*8+j  ->  y1p[t + (kt>>1)][(kt&1)*32 + quad*8 + j]
    const _Float16* w2f = (const _Float16*)(ws_c + WS_W2F);
    float4v acc[4][2];
#pragma unroll
    for (int mt = 0; mt < 4; ++mt)
#pragma unroll
        for (int nt = 0; nt < 2; ++nt)
            acc[mt][nt] = float4v{0.f, 0.f, 0.f, 0.f};

    const int tB0 = l15;                                  // 0..15 valid
    const int tB1 = (16 + l15 < TT) ? (16 + l15) : TT-1;  // clamped; garbage ignored
#pragma unroll
    for (int kt = 0; kt < 6; ++kt) {
        const int cofs = (kt & 1)*32 + quad*8;
        const int rofs = (kt >> 1);
        half8 b0 = *(const half8*)&y1p[(tB0 + rofs)*72 + cofs];
        half8 b1 = *(const half8*)&y1p[(tB1 + rofs)*72 + cofs];
#pragma unroll
        for (int mt = 0; mt < 4; ++mt) {
            half8 a = *(const half8*)(w2f + ((mt*6 + kt)*64 + lane)*8);
            acc[mt][0] = __builtin_amdgcn_mfma_f32_16x16x32_f16(a, b0, acc[mt][0], 0, 0, 0);
            acc[mt][1] = __builtin_amdgcn_mfma_f32_16x16x32_f16(a, b1, acc[mt][1], 0, 0, 0);
        }
    }
    // bias + relu -> y2 (f16) in LDS [t][ci]; C layout: col t=l15, row co=mt*16+quad*4+reg
#pragma unroll
    for (int mt = 0; mt < 4; ++mt) {
#pragma unroll
        for (int reg = 0; reg < 4; ++reg) {
            int co = mt*16 + quad*4 + reg;
            float bb = b2[co];
            y2L[l15*72 + co] = (_Float16)fmaxf(acc[mt][0][reg] + bb, 0.f);
            if (l15 < TT - 16)
                y2L[(16 + l15)*72 + co] = (_Float16)fmaxf(acc[mt][1][reg] + bb, 0.f);
        }
    }
    __syncthreads();

    // ---- Wt1 GEMM: U[t=20pad32, co=64] = y2[20,64] * Wt1[64,64], 16 MFMAs
    const _Float16* wt1f = (const _Float16*)(ws_c + WS_WT1F);
    float4v u[2][4];
#pragma unroll
    for (int mt = 0; mt < 2; ++mt)
#pragma unroll
        for (int nt = 0; nt < 4; ++nt)
            u[mt][nt] = float4v{0.f, 0.f, 0.f, 0.f};
#pragma unroll
    for (int kt = 0; kt < 2; ++kt) {
        half8 af0 = *(const half8*)&y2L[tB0*72 + kt*32 + quad*8];
        half8 af1 = *(const half8*)&y2L[tB1*72 + kt*32 + quad*8];
#pragma unroll
        for (int nt = 0; nt < 4; ++nt) {
            half8 bf = *(const half8*)(wt1f + ((kt*4 + nt)*64 + lane)*8);
            u[0][nt] = __builtin_amdgcn_mfma_f32_16x16x32_f16(af0, bf, u[0][nt], 0, 0, 0);
            u[1][nt] = __builtin_amdgcn_mfma_f32_16x16x32_f16(af1, bf, u[1][nt], 0, 0, 0);
        }
    }

    // ---- s[t] = sum_co tanh(U[t,co]+bt1[co]) * Wt2[co]  (Pade tanh, quad-reduce)
    float bt1v[4], wt2v[4];
#pragma unroll
    for (int nt = 0; nt < 4; ++nt) {
        bt1v[nt] = bt1[nt*16 + l15];
        wt2v[nt] = Wt2[nt*16 + l15];
    }
#pragma unroll
    for (int mt = 0; mt < 2; ++mt) {
#pragma unroll
        for (int reg = 0; reg < 4; ++reg) {
            int t = mt*16 + quad*4 + reg;
            float p = 0.f;
#pragma unroll
            for (int nt = 0; nt < 4; ++nt) {
                float x = u[mt][nt][reg] + bt1v[nt];
                float x2 = x * x;
                p = fmaf(x * (15.f + x2),
                         __fdividef(wt2v[nt], fmaf(6.f, x2, 15.f)), p);
            }
            p += __shfl_xor(p, 1, 64);
            p += __shfl_xor(p, 2, 64);
            p += __shfl_xor(p, 4, 64);
            p += __shfl_xor(p, 8, 64);
            if (l15 == 0 && t < TT) sbuf[t] = p;
        }
    }
    __syncthreads();

    // ---- distributed softmax over T: lane t holds exp; broadcast via shfl
    float sv = (lane < TT) ? (sbuf[lane] + bt2[0]) : -1e30f;
    float mx = sv;
#pragma unroll
    for (int off = 32; off >= 1; off >>= 1)
        mx = fmaxf(mx, __shfl_xor(mx, off, 64));
    float ev = (lane < TT) ? __expf(sv - mx) : 0.f;
    float sum = ev;
#pragma unroll
    for (int off = 32; off >= 1; off >>= 1)
        sum += __shfl_xor(sum, off, 64);
    float inv = __fdividef(1.f, sum);

    float efa = 0.f;
#pragma unroll
    for (int t = 0; t < TT; ++t)
        efa = fmaf((float)y2L[t*72 + lane], __shfl(ev, t, 64), efa);
    efa *= inv;
    efa_g[m*64 + lane] = efa;

    // ---- spatial score via 8-MFMA matvec: us = efa . Ws1 + bs1
    // A-frag rows all identical (broadcast of efa over m): a[j] = efa[kt*32+quad*8+j]
    half8 ea0, ea1;
#pragma unroll
    for (int j = 0; j < 8; ++j) {
        ea0[j] = (_Float16)__shfl(efa,      quad*8 + j, 64);
        ea1[j] = (_Float16)__shfl(efa, 32 + quad*8 + j, 64);
    }
    const _Float16* ws1f = (const _Float16*)(ws_c + WS_WS1F);
    float4v uv[4];
#pragma unroll
    for (int nt = 0; nt < 4; ++nt) uv[nt] = float4v{0.f, 0.f, 0.f, 0.f};
#pragma unroll
    for (int nt = 0; nt < 4; ++nt) {
        half8 bf0 = *(const half8*)(ws1f + ((0*4 + nt)*64 + lane)*8);
        half8 bf1 = *(const half8*)(ws1f + ((1*4 + nt)*64 + lane)*8);
        uv[nt] = __builtin_amdgcn_mfma_f32_16x16x32_f16(ea0, bf0, uv[nt], 0, 0, 0);
        uv[nt] = __builtin_amdgcn_mfma_f32_16x16x32_f16(ea1, bf1, uv[nt], 0, 0, 0);
    }
    // every lane holds us[nt*16 + l15] in uv[nt][0] (all D rows identical)
    float p = 0.f;
#pragma unroll
    for (int nt = 0; nt < 4; ++nt) {
        float x = uv[nt][0] + bs1[nt*16 + l15];
        float x2 = x * x;
        p = fmaf(x * (15.f + x2),
                 __fdividef(Ws2[nt*16 + l15], fmaf(6.f, x2, 15.f)), p);
    }
    p += __shfl_xor(p, 1, 64);
    p += __shfl_xor(p, 2, 64);
    p += __shfl_xor(p, 4, 64);
    p += __shfl_xor(p, 8, 64);
    if (lane == 0)
        score_g[m] = __expf(p + bs2[0]);   // |p| small -> safe without max-sub
}

// ---------------------------------------------------------------------------
// Kernel C: per-batch sum of exp-scores -> denom[4]. 4 blocks.
// ---------------------------------------------------------------------------
__global__ void denom_kernel(const float* __restrict__ score_g,
                             float* __restrict__ den_g)
{
    const int b = blockIdx.x;
    const int tid = threadIdx.x;     // 256
    __shared__ float red[256];
    float sum = 0.f;
    for (int i = tid; i < NNODE*NNODE; i += 256)
        sum += score_g[b*NNODE*NNODE + i];
    red[tid] = sum; __syncthreads();
    for (int w = 128; w >= 1; w >>= 1) {
        if (tid < w) red[tid] += red[tid + w];
        __syncthreads();
    }
    if (tid == 0) den_g[b] = red[0];
}

// ---------------------------------------------------------------------------
// Kernel D: node aggregation (waves split j) + 3-layer MLP (wave 0).
// ---------------------------------------------------------------------------
__launch_bounds__(256)
__global__ void node_kernel(const float* __restrict__ efa_g,
                            const float* __restrict__ e_g,
                            const float* __restrict__ den_g,
                            const float* __restrict__ Wg1,
                            const float* __restrict__ bg1,
                            const float* __restrict__ Wg2,
                            const float* __restrict__ bg2,
                            const float* __restrict__ Wout,
                            const float* __restrict__ bout,
                            float* __restrict__ out)
{
    __shared__ float part[4][64];
    const int bi   = blockIdx.x;        // b*100 + i
    const int b    = bi / NNODE;
    const int lane = threadIdx.x & 63;
    const int w    = threadIdx.x >> 6;
    const int base = bi * NNODE;

    float acc0 = 0.f, acc1 = 0.f;
    for (int j = w; j < NNODE; j += 8) {
        acc0 = fmaf(e_g[base + j], efa_g[(base + j)*64 + lane], acc0);
        int j2 = j + 4;
        if (j2 < NNODE)
            acc1 = fmaf(e_g[base + j2], efa_g[(base + j2)*64 + lane], acc1);
    }
    part[w][lane] = acc0 + acc1;
    __syncthreads();
    if (w != 0) return;

    const float invden = __fdividef(1.f, den_g[b]);
    float node = (part[0][lane] + part[1][lane] + part[2][lane] + part[3][lane]) * invden;

    float a0 = bg1[lane], a1 = 0.f, a2 = 0.f, a3 = 0.f;
#pragma unroll
    for (int ci = 0; ci < HH; ci += 4) {
        a0 = fmaf(__shfl(node, ci + 0, 64), Wg1[(ci + 0)*HH + lane], a0);
        a1 = fmaf(__shfl(node, ci + 1, 64), Wg1[(ci + 1)*HH + lane], a1);
        a2 = fmaf(__shfl(node, ci + 2, 64), Wg1[(ci + 2)*HH + lane], a2);
        a3 = fmaf(__shfl(node, ci + 3, 64), Wg1[(ci + 3)*HH + lane], a3);
    }
    float g1 = fmaxf((a0 + a1) + (a2 + a3), 0.f);

    a0 = bg2[lane]; a1 = 0.f; a2 = 0.f; a3 = 0.f;
#pragma unroll
    for (int ci = 0; ci < HH; ci += 4) {
        a0 = fmaf(__shfl(g1, ci + 0, 64), Wg2[(ci + 0)*HH + lane], a0);
        a1 = fmaf(__shfl(g1, ci + 1, 64), Wg2[(ci + 1)*HH + lane], a1);
        a2 = fmaf(__shfl(g1, ci + 2, 64), Wg2[(ci + 2)*HH + lane], a2);
        a3 = fmaf(__shfl(g1, ci + 3, 64), Wg2[(ci + 3)*HH + lane], a3);
    }
    float g2 = fmaxf((a0 + a1) + (a2 + a3), 0.f);

    float o0 = bout[lane], o1 = bout[lane + 64];
    float q0 = 0.f, q1 = 0.f;
#pragma unroll
    for (int ci = 0; ci < HH; ci += 2) {
        float ga = __shfl(g2, ci, 64), gb = __shfl(g2, ci + 1, 64);
        o0 = fmaf(ga, Wout[ci*OO + lane],            o0);
        o1 = fmaf(ga, Wout[ci*OO + lane + 64],       o1);
        q0 = fmaf(gb, Wout[(ci + 1)*OO + lane],      q0);
        q1 = fmaf(gb, Wout[(ci + 1)*OO + lane + 64], q1);
    }
    out[bi*OO + lane]      = fmaxf(o0 + q0, 0.f);
    out[bi*OO + lane + 64] = fmaxf(o1 + q1, 0.f);
}

// ---------------------------------------------------------------------------
extern "C" void kernel_launch(void* const* d_in, const int* in_sizes, int n_in,
                              void* d_out, int out_size, void* d_ws, size_t ws_size,
                              hipStream_t stream)
{
    const float* ew      = (const float*)d_in[0];
    const float* W_edge  = (const float*)d_in[1];
    const float* b_edge  = (const float*)d_in[2];
    const float* conv1_w = (const float*)d_in[3];
    const float* conv1_b = (const float*)d_in[4];
    const float* conv2_w = (const float*)d_in[5];
    const float* conv2_b = (const float*)d_in[6];
    const float* Wt1     = (const float*)d_in[7];
    const float* bt1     = (const float*)d_in[8];
    const float* Wt2     = (const float*)d_in[9];
    const float* bt2     = (const float*)d_in[10];
    const float* Ws1     = (const float*)d_in[11];
    const float* bs1     = (const float*)d_in[12];
    const float* Ws2     = (const float*)d_in[13];
    const float* bs2     = (const float*)d_in[14];
    const float* Wg1     = (const float*)d_in[15];
    const float* bg1     = (const float*)d_in[16];
    const float* Wg2     = (const float*)d_in[17];
    const float* bg2     = (const float*)d_in[18];
    const float* Wout    = (const float*)d_in[19];
    const float* bout    = (const float*)d_in[20];

    float* ws  = (float*)d_ws;
    float* out = (float*)d_out;

    prep_kernel<<<16, 256, 0, stream>>>(W_edge, b_edge, conv1_w, conv1_b, conv2_w,
                                        Wt1, Ws1, ws);

    edge_kernel<<<M, 64, 0, stream>>>(ew, ws, conv2_b,
                                      bt1, Wt2, bt2,
                                      bs1, Ws2, bs2,
                                      ws + WS_EFA, ws + WS_ESC);

    denom_kernel<<<BN, 256, 0, stream>>>(ws + WS_ESC, ws + WS_DEN);

    node_kernel<<<BN*NNODE, 256, 0, stream>>>(ws + WS_EFA, ws + WS_ESC, ws + WS_DEN,
                                              Wg1, bg1, Wg2, bg2, Wout, bout, out);
}

// Round 6
// 236.231 us; speedup vs baseline: 2.7144x; 1.0120x over previous
//
#include <hip/hip_runtime.h>
#include <math.h>

// Problem constants
#define BN 4
#define NNODE 100
#define TT 20
#define HH 64
#define OO 128
#define M (BN*NNODE*NNODE)   // 40000 edges
#define EPB 2                // edges (waves) per block; private LDS slice per wave

// Workspace layout (float offsets)
#define WS_A1   0                       // A1[k][co], 3*64
#define WS_C3   192                     // c_t0[64], c_full[64], c_tL[64]
#define WS_W2F  384                     // w2 A-frags (f16): 24*512 halfs = 6144 floats
#define WS_WT1F (WS_W2F + 6144)         // Wt1 B-frags (f16): 8*512 halfs = 2048 floats
#define WS_WS1F (WS_WT1F + 2048)        // Ws1 B-frags (f16): 8*512 halfs = 2048 floats
#define WS_DEN  (WS_WS1F + 2048)        // denom[4]
#define WS_EFA  (WS_DEN + 4)            // efa[M*64]
#define WS_ESC  (WS_EFA + M*64)         // exp(scores) [M]

typedef _Float16 half8 __attribute__((ext_vector_type(8)));
typedef float float4v __attribute__((ext_vector_type(4)));

// Pade(3,2): tanh(x) ~ x(15+x^2)/(15+6x^2), |err|<3e-4 for |x|<=1 (|x|~0.2 here)
__device__ __forceinline__ float pade_tanh(float x) {
    float x2 = x * x;
    return (x * (15.f + x2)) * __fdividef(1.f, fmaf(6.f, x2, 15.f));
}

// ---------------------------------------------------------------------------
// Kernel A: fold edge-embedding + conv1 into rank-1 constants; pack MFMA frags
// for w2 (A-operand), Wt1 (B-operand), Ws1 (B-operand).
// ---------------------------------------------------------------------------
__global__ void prep_kernel(const float* __restrict__ W_edge,
                            const float* __restrict__ b_edge,
                            const float* __restrict__ w1,
                            const float* __restrict__ b1,
                            const float* __restrict__ w2,
                            const float* __restrict__ Wt1,
                            const float* __restrict__ Ws1,
                            float* __restrict__ ws)
{
    const int tid  = blockIdx.x * blockDim.x + threadIdx.x;
    const int nthr = gridDim.x * blockDim.x;
    if (tid < 64) {
        int co = tid;
        float a[3] = {0.f, 0.f, 0.f};
        float bk[3] = {0.f, 0.f, 0.f};
        for (int ci = 0; ci < HH; ++ci) {
            float we = W_edge[ci], be = b_edge[ci];
#pragma unroll
            for (int k = 0; k < 3; ++k) {
                float w = w1[(co*HH + ci)*3 + k];
                a[k]  = fmaf(we, w, a[k]);
                bk[k] = fmaf(be, w, bk[k]);
            }
        }
        float bb = b1[co];
        ws[WS_A1 + 0*64 + co] = a[0];
        ws[WS_A1 + 1*64 + co] = a[1];
        ws[WS_A1 + 2*64 + co] = a[2];
        ws[WS_C3 +        co] = bb + bk[1] + bk[2];          // t == 0
        ws[WS_C3 +  64 +  co] = bb + bk[0] + bk[1] + bk[2];  // interior
        ws[WS_C3 + 128 +  co] = bb + bk[0] + bk[1];          // t == T-1
    }
    _Float16* w2f  = (_Float16*)(ws + WS_W2F);
    _Float16* wt1f = (_Float16*)(ws + WS_WT1F);
    _Float16* ws1f = (_Float16*)(ws + WS_WS1F);
    // w2 A-frags: co = mt*16+(lane&15), q = kt*32+(lane>>4)*8+j, q = k*64+ci
    for (int s = tid; s < 24*64*8; s += nthr) {
        int j    = s & 7;
        int lane = (s >> 3) & 63;
        int f    = s >> 9;           // 0..23
        int mt = f / 6, kt = f % 6;
        int co = mt*16 + (lane & 15);
        int q  = kt*32 + ((lane >> 4) << 3) + j;
        int k  = q >> 6, ci = q & 63;
        w2f[f*512 + lane*8 + j] = (_Float16)w2[(co*HH + ci)*3 + k];
    }
    // Wt1 / Ws1 B-frags: ci = kt*32+(lane>>4)*8+j, co = nt*16+(lane&15)
    for (int s = tid; s < 8*64*8; s += nthr) {
        int j    = s & 7;
        int lane = (s >> 3) & 63;
        int f    = s >> 9;           // 0..7
        int kt = f / 4, nt = f % 4;
        int ci = kt*32 + ((lane >> 4) << 3) + j;
        int co = nt*16 + (lane & 15);
        wt1f[f*512 + lane*8 + j] = (_Float16)Wt1[ci*HH + co];
        ws1f[f*512 + lane*8 + j] = (_Float16)Ws1[ci*HH + co];
    }
}

// ---------------------------------------------------------------------------
// Kernel B: EPB waves per block, one edge per wave, private LDS slice per
// wave, NO barriers, NO atomics. conv1 (rank-1, fp32) -> conv2 (MFMA f16,
// shifted-window B reads) -> temporal attention (MFMA + distributed softmax)
// -> efa + spatial score (8-MFMA matvec).
// ---------------------------------------------------------------------------
__launch_bounds__(EPB*64)
__global__ void edge_kernel(const float* __restrict__ ew_g,
                            const float* __restrict__ ws_c,
                            const float* __restrict__ b2,
                            const float* __restrict__ bt1,
                            const float* __restrict__ Wt2,
                            const float* __restrict__ bt2,
                            const float* __restrict__ bs1,
                            const float* __restrict__ Ws2,
                            const float* __restrict__ bs2,
                            float* __restrict__ efa_g,
                            float* __restrict__ score_g)
{
    __shared__ _Float16 y1p[EPB][22*72];  // padded y1 rows 0/21 zero (3168 B/slice)
    __shared__ _Float16 y2L[EPB][TT*72];  // y2 [t][ci] (2880 B/slice)
    __shared__ float    sbuf[EPB][TT];
    __shared__ float    ewp[EPB][22];

    const int w    = threadIdx.x >> 6;
    const int lane = threadIdx.x & 63;
    const int m    = blockIdx.x * EPB + w;
    const int l15  = lane & 15;
    const int quad = lane >> 4;

    if (lane < TT)      ewp[w][lane + 1] = ew_g[m*TT + lane];
    else if (lane < 22) ewp[w][(lane - TT) * 21] = 0.f;   // lane20->[0], lane21->[21]

    const float a0 = ws_c[WS_A1 +       lane];
    const float a1 = ws_c[WS_A1 +  64 + lane];
    const float a2 = ws_c[WS_A1 + 128 + lane];
    const float c0 = ws_c[WS_C3 +       lane];
    const float cf = ws_c[WS_C3 +  64 + lane];
    const float cL = ws_c[WS_C3 + 128 + lane];

    // ---- conv1 (3 FMA per t) + relu -> padded LDS; lane = channel ci
    y1p[w][lane] = (_Float16)0.f;          // row 0
    y1p[w][21*72 + lane] = (_Float16)0.f;  // row 21
#pragma unroll
    for (int t = 0; t < TT; ++t) {
        float c = (t == 0) ? c0 : (t == TT-1) ? cL : cf;
        float v = fmaf(a0, ewp[w][t], fmaf(a1, ewp[w][t+1], fmaf(a2, ewp[w][t+2], c)));
        y1p[w][(t+1)*72 + lane] = (_Float16)fmaxf(v, 0.f);
    }

    // ---- conv2 GEMM: D[co=64, t=20pad32] = A[64,192] * B[192,t], 48 MFMAs
    // B elem q=kt*32+quad*8+j  ->  y1p[t + (kt>>1)][(kt&1)*32 + quad*8 + j]
    const _Float16* w2f = (const _Float16*)(ws_c + WS_W2F);
    float4v acc[4][2];
#pragma unroll
    for (int mt = 0; mt < 4; ++mt)
#pragma unroll
        for (int nt = 0; nt < 2; ++nt)
            acc[mt][nt] = float4v{0.f, 0.f, 0.f, 0.f};

    const int tB0 = l15;                                  // 0..15 valid
    const int tB1 = (16 + l15 < TT) ? (16 + l15) : TT-1;  // clamped; garbage ignored
#pragma unroll
    for (int kt = 0; kt < 6; ++kt) {
        const int cofs = (kt & 1)*32 + quad*8;
        const int rofs = (kt >> 1);
        half8 b0 = *(const half8*)&y1p[w][(tB0 + rofs)*72 + cofs];
        half8 b1 = *(const half8*)&y1p[w][(tB1 + rofs)*72 + cofs];
#pragma unroll
        for (int mt = 0; mt < 4; ++mt) {
            half8 a = *(const half8*)(w2f + ((mt*6 + kt)*64 + lane)*8);
            acc[mt][0] = __builtin_amdgcn_mfma_f32_16x16x32_f16(a, b0, acc[mt][0], 0, 0, 0);
            acc[mt][1] = __builtin_amdgcn_mfma_f32_16x16x32_f16(a, b1, acc[mt][1], 0, 0, 0);
        }
    }
    // bias + relu -> y2 (f16) in LDS [t][ci]; C layout: col t=l15, row co=mt*16+quad*4+reg
#pragma unroll
    for (int mt = 0; mt < 4; ++mt) {
#pragma unroll
        for (int reg = 0; reg < 4; ++reg) {
            int co = mt*16 + quad*4 + reg;
            float bb = b2[co];
            y2L[w][l15*72 + co] = (_Float16)fmaxf(acc[mt][0][reg] + bb, 0.f);
            if (l15 < TT - 16)
                y2L[w][(16 + l15)*72 + co] = (_Float16)fmaxf(acc[mt][1][reg] + bb, 0.f);
        }
    }

    // ---- Wt1 GEMM: U[t=20pad32, co=64] = y2[20,64] * Wt1[64,64], 16 MFMAs
    const _Float16* wt1f = (const _Float16*)(ws_c + WS_WT1F);
    float4v u[2][4];
#pragma unroll
    for (int mt = 0; mt < 2; ++mt)
#pragma unroll
        for (int nt = 0; nt < 4; ++nt)
            u[mt][nt] = float4v{0.f, 0.f, 0.f, 0.f};
#pragma unroll
    for (int kt = 0; kt < 2; ++kt) {
        half8 af0 = *(const half8*)&y2L[w][tB0*72 + kt*32 + quad*8];
        half8 af1 = *(const half8*)&y2L[w][tB1*72 + kt*32 + quad*8];
#pragma unroll
        for (int nt = 0; nt < 4; ++nt) {
            half8 bf = *(const half8*)(wt1f + ((kt*4 + nt)*64 + lane)*8);
            u[0][nt] = __builtin_amdgcn_mfma_f32_16x16x32_f16(af0, bf, u[0][nt], 0, 0, 0);
            u[1][nt] = __builtin_amdgcn_mfma_f32_16x16x32_f16(af1, bf, u[1][nt], 0, 0, 0);
        }
    }

    // ---- s[t] = sum_co tanh(U[t,co]+bt1[co]) * Wt2[co]  (Pade tanh, quad-reduce)
    float bt1v[4], wt2v[4];
#pragma unroll
    for (int nt = 0; nt < 4; ++nt) {
        bt1v[nt] = bt1[nt*16 + l15];
        wt2v[nt] = Wt2[nt*16 + l15];
    }
#pragma unroll
    for (int mt = 0; mt < 2; ++mt) {
#pragma unroll
        for (int reg = 0; reg < 4; ++reg) {
            int t = mt*16 + quad*4 + reg;
            float p = 0.f;
#pragma unroll
            for (int nt = 0; nt < 4; ++nt) {
                float x = u[mt][nt][reg] + bt1v[nt];
                float x2 = x * x;
                p = fmaf(x * (15.f + x2),
                         __fdividef(wt2v[nt], fmaf(6.f, x2, 15.f)), p);
            }
            p += __shfl_xor(p, 1, 64);
            p += __shfl_xor(p, 2, 64);
            p += __shfl_xor(p, 4, 64);
            p += __shfl_xor(p, 8, 64);
            if (l15 == 0 && t < TT) sbuf[w][t] = p;
        }
    }

    // ---- distributed softmax over T: lane t holds exp; broadcast via shfl
    float sv = (lane < TT) ? (sbuf[w][lane] + bt2[0]) : -1e30f;
    float mx = sv;
#pragma unroll
    for (int off = 32; off >= 1; off >>= 1)
        mx = fmaxf(mx, __shfl_xor(mx, off, 64));
    float ev = (lane < TT) ? __expf(sv - mx) : 0.f;
    float sum = ev;
#pragma unroll
    for (int off = 32; off >= 1; off >>= 1)
        sum += __shfl_xor(sum, off, 64);
    float inv = __fdividef(1.f, sum);

    float efa = 0.f;
#pragma unroll
    for (int t = 0; t < TT; ++t)
        efa = fmaf((float)y2L[w][t*72 + lane], __shfl(ev, t, 64), efa);
    efa *= inv;
    efa_g[m*64 + lane] = efa;

    // ---- spatial score via 8-MFMA matvec: us = efa . Ws1 + bs1
    half8 ea0, ea1;
#pragma unroll
    for (int j = 0; j < 8; ++j) {
        ea0[j] = (_Float16)__shfl(efa,      quad*8 + j, 64);
        ea1[j] = (_Float16)__shfl(efa, 32 + quad*8 + j, 64);
    }
    const _Float16* ws1f = (const _Float16*)(ws_c + WS_WS1F);
    float4v uv[4];
#pragma unroll
    for (int nt = 0; nt < 4; ++nt) uv[nt] = float4v{0.f, 0.f, 0.f, 0.f};
#pragma unroll
    for (int nt = 0; nt < 4; ++nt) {
        half8 bf0 = *(const half8*)(ws1f + ((0*4 + nt)*64 + lane)*8);
        half8 bf1 = *(const half8*)(ws1f + ((1*4 + nt)*64 + lane)*8);
        uv[nt] = __builtin_amdgcn_mfma_f32_16x16x32_f16(ea0, bf0, uv[nt], 0, 0, 0);
        uv[nt] = __builtin_amdgcn_mfma_f32_16x16x32_f16(ea1, bf1, uv[nt], 0, 0, 0);
    }
    // every lane holds us[nt*16 + l15] in uv[nt][0] (all D rows identical)
    float p = 0.f;
#pragma unroll
    for (int nt = 0; nt < 4; ++nt) {
        float x = uv[nt][0] + bs1[nt*16 + l15];
        float x2 = x * x;
        p = fmaf(x * (15.f + x2),
                 __fdividef(Ws2[nt*16 + l15], fmaf(6.f, x2, 15.f)), p);
    }
    p += __shfl_xor(p, 1, 64);
    p += __shfl_xor(p, 2, 64);
    p += __shfl_xor(p, 4, 64);
    p += __shfl_xor(p, 8, 64);
    if (lane == 0)
        score_g[m] = __expf(p + bs2[0]);   // |p| small -> safe without max-sub
}

// ---------------------------------------------------------------------------
// Kernel C: per-batch sum of exp-scores -> denom[4]. 4 blocks.
// ---------------------------------------------------------------------------
__global__ void denom_kernel(const float* __restrict__ score_g,
                             float* __restrict__ den_g)
{
    const int b = blockIdx.x;
    const int tid = threadIdx.x;     // 256
    __shared__ float red[256];
    float sum = 0.f;
    for (int i = tid; i < NNODE*NNODE; i += 256)
        sum += score_g[b*NNODE*NNODE + i];
    red[tid] = sum; __syncthreads();
    for (int w = 128; w >= 1; w >>= 1) {
        if (tid < w) red[tid] += red[tid + w];
        __syncthreads();
    }
    if (tid == 0) den_g[b] = red[0];
}

// ---------------------------------------------------------------------------
// Kernel D: node aggregation (waves split j) + 3-layer MLP (wave 0).
// ---------------------------------------------------------------------------
__launch_bounds__(256)
__global__ void node_kernel(const float* __restrict__ efa_g,
                            const float* __restrict__ e_g,
                            const float* __restrict__ den_g,
                            const float* __restrict__ Wg1,
                            const float* __restrict__ bg1,
                            const float* __restrict__ Wg2,
                            const float* __restrict__ bg2,
                            const float* __restrict__ Wout,
                            const float* __restrict__ bout,
                            float* __restrict__ out)
{
    __shared__ float part[4][64];
    const int bi   = blockIdx.x;        // b*100 + i
    const int b    = bi / NNODE;
    const int lane = threadIdx.x & 63;
    const int w    = threadIdx.x >> 6;
    const int base = bi * NNODE;

    float acc0 = 0.f, acc1 = 0.f;
    for (int j = w; j < NNODE; j += 8) {
        acc0 = fmaf(e_g[base + j], efa_g[(base + j)*64 + lane], acc0);
        int j2 = j + 4;
        if (j2 < NNODE)
            acc1 = fmaf(e_g[base + j2], efa_g[(base + j2)*64 + lane], acc1);
    }
    part[w][lane] = acc0 + acc1;
    __syncthreads();
    if (w != 0) return;

    const float invden = __fdividef(1.f, den_g[b]);
    float node = (part[0][lane] + part[1][lane] + part[2][lane] + part[3][lane]) * invden;

    float a0 = bg1[lane], a1 = 0.f, a2 = 0.f, a3 = 0.f;
#pragma unroll
    for (int ci = 0; ci < HH; ci += 4) {
        a0 = fmaf(__shfl(node, ci + 0, 64), Wg1[(ci + 0)*HH + lane], a0);
        a1 = fmaf(__shfl(node, ci + 1, 64), Wg1[(ci + 1)*HH + lane], a1);
        a2 = fmaf(__shfl(node, ci + 2, 64), Wg1[(ci + 2)*HH + lane], a2);
        a3 = fmaf(__shfl(node, ci + 3, 64), Wg1[(ci + 3)*HH + lane], a3);
    }
    float g1 = fmaxf((a0 + a1) + (a2 + a3), 0.f);

    a0 = bg2[lane]; a1 = 0.f; a2 = 0.f; a3 = 0.f;
#pragma unroll
    for (int ci = 0; ci < HH; ci += 4) {
        a0 = fmaf(__shfl(g1, ci + 0, 64), Wg2[(ci + 0)*HH + lane], a0);
        a1 = fmaf(__shfl(g1, ci + 1, 64), Wg2[(ci + 1)*HH + lane], a1);
        a2 = fmaf(__shfl(g1, ci + 2, 64), Wg2[(ci + 2)*HH + lane], a2);
        a3 = fmaf(__shfl(g1, ci + 3, 64), Wg2[(ci + 3)*HH + lane], a3);
    }
    float g2 = fmaxf((a0 + a1) + (a2 + a3), 0.f);

    float o0 = bout[lane], o1 = bout[lane + 64];
    float q0 = 0.f, q1 = 0.f;
#pragma unroll
    for (int ci = 0; ci < HH; ci += 2) {
        float ga = __shfl(g2, ci, 64), gb = __shfl(g2, ci + 1, 64);
        o0 = fmaf(ga, Wout[ci*OO + lane],            o0);
        o1 = fmaf(ga, Wout[ci*OO + lane + 64],       o1);
        q0 = fmaf(gb, Wout[(ci + 1)*OO + lane],      q0);
        q1 = fmaf(gb, Wout[(ci + 1)*OO + lane + 64], q1);
    }
    out[bi*OO + lane]      = fmaxf(o0 + q0, 0.f);
    out[bi*OO + lane + 64] = fmaxf(o1 + q1, 0.f);
}

// ---------------------------------------------------------------------------
extern "C" void kernel_launch(void* const* d_in, const int* in_sizes, int n_in,
                              void* d_out, int out_size, void* d_ws, size_t ws_size,
                              hipStream_t stream)
{
    const float* ew      = (const float*)d_in[0];
    const float* W_edge  = (const float*)d_in[1];
    const float* b_edge  = (const float*)d_in[2];
    const float* conv1_w = (const float*)d_in[3];
    const float* conv1_b = (const float*)d_in[4];
    const float* conv2_w = (const float*)d_in[5];
    const float* conv2_b = (const float*)d_in[6];
    const float* Wt1     = (const float*)d_in[7];
    const float* bt1     = (const float*)d_in[8];
    const float* Wt2     = (const float*)d_in[9];
    const float* bt2     = (const float*)d_in[10];
    const float* Ws1     = (const float*)d_in[11];
    const float* bs1     = (const float*)d_in[12];
    const float* Ws2     = (const float*)d_in[13];
    const float* bs2     = (const float*)d_in[14];
    const float* Wg1     = (const float*)d_in[15];
    const float* bg1     = (const float*)d_in[16];
    const float* Wg2     = (const float*)d_in[17];
    const float* bg2     = (const float*)d_in[18];
    const float* Wout    = (const float*)d_in[19];
    const float* bout    = (const float*)d_in[20];

    float* ws  = (float*)d_ws;
    float* out = (float*)d_out;

    prep_kernel<<<16, 256, 0, stream>>>(W_edge, b_edge, conv1_w, conv1_b, conv2_w,
                                        Wt1, Ws1, ws);

    edge_kernel<<<M/EPB, EPB*64, 0, stream>>>(ew, ws, conv2_b,
                                              bt1, Wt2, bt2,
                                              bs1, Ws2, bs2,
                                              ws + WS_EFA, ws + WS_ESC);

    denom_kernel<<<BN, 256, 0, stream>>>(ws + WS_ESC, ws + WS_DEN);

    node_kernel<<<BN*NNODE, 256, 0, stream>>>(ws + WS_EFA, ws + WS_ESC, ws + WS_DEN,
                                              Wg1, bg1, Wg2, bg2, Wout, bout, out);
}